// Round 1
// baseline (259.316 us; speedup 1.0000x reference)
//
#include <hip/hip_runtime.h>
#include <stdint.h>

#define BB 8
#define NN 2048
#define DD 64
#define DELTA 0.1625f
#define FREQ_SCALE 0.325f

typedef __bf16 bf16x8 __attribute__((ext_vector_type(8)));
typedef float f32x4 __attribute__((ext_vector_type(4)));
typedef unsigned int u32x4 __attribute__((ext_vector_type(4)));

static __device__ __forceinline__ unsigned short f2b(float x) {
    union { float f; unsigned int u; } c; c.f = x;
    unsigned int r = (c.u + 0x7FFFu + ((c.u >> 16) & 1u)) >> 16;
    return (unsigned short)r;
}

// ---------------- prep 1: normalize embeddings, echo layers, e0 (f32) + e0^T (bf16)
__global__ __launch_bounds__(256) void prep_norm(
        const float* __restrict__ emb, const float* __restrict__ freq,
        float* __restrict__ e0, unsigned short* __restrict__ eT0,
        int* __restrict__ echo) {
    __shared__ unsigned short tile[64][72];
    int t = threadIdx.x;
    int tok0 = blockIdx.x * 64;            // global token base (block stays in one batch)
    int lt = t >> 2;                       // local token 0..63
    int tt = tok0 + lt;                    // global token
    int dd = (t & 3) * 16;

    const float* src = emb + (size_t)tt * DD + dd;
    f32x4 v[4];
    float ss = 0.f;
    #pragma unroll
    for (int q = 0; q < 4; q++) {
        v[q] = *(const f32x4*)(src + q * 4);
        ss += v[q].x*v[q].x + v[q].y*v[q].y + v[q].z*v[q].z + v[q].w*v[q].w;
    }
    ss += __shfl_xor(ss, 1);
    ss += __shfl_xor(ss, 2);
    float scale = 1.f / fmaxf(sqrtf(ss), 1e-12f);
    float* dst = e0 + (size_t)tt * DD + dd;
    #pragma unroll
    for (int q = 0; q < 4; q++) {
        f32x4 o = v[q] * scale;
        *(f32x4*)(dst + q * 4) = o;
        tile[lt][dd + q*4 + 0] = f2b(o.x);
        tile[lt][dd + q*4 + 1] = f2b(o.y);
        tile[lt][dd + q*4 + 2] = f2b(o.z);
        tile[lt][dd + q*4 + 3] = f2b(o.w);
    }
    if ((t & 3) == 0) {
        int el = 1 + (int)floorf(freq[tt] * FREQ_SCALE);
        el = el < 1 ? 1 : (el > 5 ? 5 : el);
        echo[tt] = el;
    }
    __syncthreads();
    int b  = tok0 / NN;
    int tb = tok0 % NN;
    for (int idx = t; idx < 64 * 64; idx += 256) {
        int d = idx >> 6, j = idx & 63;
        eT0[((size_t)b * DD + d) * NN + tb + j] = tile[j][d];
    }
}

// ---------------- prep 2: rowsum (full row, diag cancels algebraically) + bf16 cast of rm
__global__ __launch_bounds__(256) void prep_rowsum(
        const float* __restrict__ rm, float* __restrict__ rowsum,
        unsigned short* __restrict__ rmb, int cached) {
    __shared__ float wsum[4];
    int row = blockIdx.x;                  // 0 .. B*N-1
    size_t base = (size_t)row * NN;
    int t = threadIdx.x;
    const float* p = rm + base + (size_t)t * 8;
    f32x4 a = *(const f32x4*)p;
    f32x4 c = *(const f32x4*)(p + 4);
    float s = a.x+a.y+a.z+a.w + c.x+c.y+c.z+c.w;
    if (cached) {
        u32x4 o;
        o.x = (unsigned)f2b(a.x) | ((unsigned)f2b(a.y) << 16);
        o.y = (unsigned)f2b(a.z) | ((unsigned)f2b(a.w) << 16);
        o.z = (unsigned)f2b(c.x) | ((unsigned)f2b(c.y) << 16);
        o.w = (unsigned)f2b(c.z) | ((unsigned)f2b(c.w) << 16);
        *(u32x4*)(rmb + base + (size_t)t * 8) = o;
    }
    #pragma unroll
    for (int m = 1; m < 64; m <<= 1) s += __shfl_xor(s, m);
    if ((t & 63) == 0) wsum[t >> 6] = s;
    __syncthreads();
    if (t == 0) rowsum[row] = wsum[0] + wsum[1] + wsum[2] + wsum[3];
}

// ---------------- layer step: agg^T = e^T * rm^T via MFMA, fused shift + l2norm epilogue
template<bool CACHED>
__global__ __launch_bounds__(512) void layer_step(
        const void* __restrict__ rm_,               // bf16 cache or raw f32
        const unsigned short* __restrict__ eT_src,  // [B][64][N] bf16
        const float* __restrict__ e_src,            // [B][N][64] f32
        const float* __restrict__ rowsum,
        const int* __restrict__ echo,
        float* __restrict__ e_dst,
        unsigned short* __restrict__ eT_dst,
        int layer) {
    __shared__ float red[4 * 64 * 16];   // K-half partials, 16KB
    int t = threadIdx.x;
    int w = t >> 6, l = t & 63;
    int b = blockIdx.y;
    int i0 = blockIdx.x * 64;
    int wi = w & 3;            // i-tile within block
    int kh = w >> 2;           // K half 0/1
    int lane_lo = l & 15, lane_hi = l >> 4;
    int i = i0 + wi * 16 + lane_lo;

    f32x4 acc[4] = {};
    size_t rm_row = ((size_t)b * NN + i) * NN;
    int kbase = kh * (NN / 2) + 8 * lane_hi;
    const unsigned short* eT_b = eT_src + (size_t)b * DD * NN;

    #pragma unroll 4
    for (int kk = 0; kk < NN / 2; kk += 32) {
        int k0 = kbase + kk;
        bf16x8 bfrag;
        if (CACHED) {
            const unsigned short* rmb = (const unsigned short*)rm_;
            bfrag = __builtin_bit_cast(bf16x8, *(const u32x4*)(rmb + rm_row + k0));
        } else {
            const float* rmf = (const float*)rm_;
            f32x4 lo = *(const f32x4*)(rmf + rm_row + k0);
            f32x4 hi = *(const f32x4*)(rmf + rm_row + k0 + 4);
            u32x4 o;
            o.x = (unsigned)f2b(lo.x) | ((unsigned)f2b(lo.y) << 16);
            o.y = (unsigned)f2b(lo.z) | ((unsigned)f2b(lo.w) << 16);
            o.z = (unsigned)f2b(hi.x) | ((unsigned)f2b(hi.y) << 16);
            o.w = (unsigned)f2b(hi.z) | ((unsigned)f2b(hi.w) << 16);
            bfrag = __builtin_bit_cast(bf16x8, o);
        }
        #pragma unroll
        for (int f = 0; f < 4; f++) {
            bf16x8 afrag = __builtin_bit_cast(bf16x8,
                *(const u32x4*)(eT_b + ((size_t)(16*f + lane_lo)) * NN + k0));
            acc[f] = __builtin_amdgcn_mfma_f32_16x16x32_bf16(afrag, bfrag, acc[f], 0, 0, 0);
        }
    }

    if (kh == 1) {
        float* dp = red + ((size_t)wi * 64 + l) * 16;
        #pragma unroll
        for (int f = 0; f < 4; f++) *(f32x4*)(dp + 4*f) = acc[f];
    }
    __syncthreads();
    if (kh == 0) {
        const float* sp = red + ((size_t)wi * 64 + l) * 16;
        #pragma unroll
        for (int f = 0; f < 4; f++) acc[f] += *(const f32x4*)(sp + 4*f);

        // acc[f][r] = agg[i][d],  d = 16*f + 4*lane_hi + r,  i = i0 + wi*16 + lane_lo
        size_t gi = (size_t)b * NN + i;
        float rs = rowsum[gi];
        float active = (layer < echo[gi]) ? 1.f : 0.f;
        float coef = DELTA * active;
        size_t ebase = gi * DD;
        f32x4 upd[4];
        float ss = 0.f;
        #pragma unroll
        for (int f = 0; f < 4; f++) {
            f32x4 e = *(const f32x4*)(e_src + ebase + 16*f + 4*lane_hi);
            f32x4 u = e + coef * (e * rs - acc[f]);
            upd[f] = u;
            ss += u.x*u.x + u.y*u.y + u.z*u.z + u.w*u.w;
        }
        ss += __shfl_xor(ss, 16);
        ss += __shfl_xor(ss, 32);
        float scale = 1.f / fmaxf(sqrtf(ss), 1e-12f);
        unsigned short* ep = eT_dst + (size_t)b * DD * NN;
        #pragma unroll
        for (int f = 0; f < 4; f++) {
            f32x4 o = upd[f] * scale;
            *(f32x4*)(e_dst + ebase + 16*f + 4*lane_hi) = o;
            int dbase = 16*f + 4*lane_hi;
            ep[(size_t)(dbase + 0) * NN + i] = f2b(o.x);
            ep[(size_t)(dbase + 1) * NN + i] = f2b(o.y);
            ep[(size_t)(dbase + 2) * NN + i] = f2b(o.z);
            ep[(size_t)(dbase + 3) * NN + i] = f2b(o.w);
        }
    }
}

extern "C" void kernel_launch(void* const* d_in, const int* in_sizes, int n_in,
                              void* d_out, int out_size, void* d_ws, size_t ws_size,
                              hipStream_t stream) {
    const float* emb  = (const float*)d_in[0];
    const float* freq = (const float*)d_in[1];
    const float* rm   = (const float*)d_in[2];
    float* out = (float*)d_out;
    char* ws = (char*)d_ws;

    const size_t eBytes  = (size_t)BB * NN * DD * 4;   // 4 MB
    const size_t eTBytes = (size_t)BB * DD * NN * 2;   // 2 MB
    float* e_f32[2] = { (float*)ws, (float*)(ws + eBytes) };
    unsigned short* eT[2] = { (unsigned short*)(ws + 2*eBytes),
                              (unsigned short*)(ws + 2*eBytes + eTBytes) };
    float* rowsum = (float*)(ws + 2*eBytes + 2*eTBytes);
    int* echo = (int*)(ws + 2*eBytes + 2*eTBytes + (size_t)BB*NN*4);
    unsigned short* rmb = (unsigned short*)(ws + 2*eBytes + 2*eTBytes + 2*(size_t)BB*NN*4);
    size_t need_cached = 2*eBytes + 2*eTBytes + 2*(size_t)BB*NN*4 + (size_t)BB*NN*NN*2;
    int cached = (ws_size >= need_cached) ? 1 : 0;

    prep_norm<<<dim3(BB*NN/64), dim3(256), 0, stream>>>(emb, freq, e_f32[0], eT[0], echo);
    prep_rowsum<<<dim3(BB*NN), dim3(256), 0, stream>>>(rm, rowsum, rmb, cached);

    for (int l = 0; l < 5; l++) {
        float* dst = (l == 4) ? out : e_f32[(l + 1) & 1];
        if (cached)
            layer_step<true><<<dim3(NN/64, BB), dim3(512), 0, stream>>>(
                (const void*)rmb, eT[l & 1], e_f32[l & 1], rowsum, echo,
                dst, eT[(l + 1) & 1], l);
        else
            layer_step<false><<<dim3(NN/64, BB), dim3(512), 0, stream>>>(
                (const void*)rm, eT[l & 1], e_f32[l & 1], rowsum, echo,
                dst, eT[(l + 1) & 1], l);
    }
}

// Round 2
// 214.526 us; speedup vs baseline: 1.2088x; 1.2088x over previous
//
#include <hip/hip_runtime.h>
#include <stdint.h>

#define BB 8
#define NN 2048
#define DD 64
#define DELTA 0.1625f
#define FREQ_SCALE 0.325f

typedef __bf16 bf16x8 __attribute__((ext_vector_type(8)));
typedef float f32x4 __attribute__((ext_vector_type(4)));
typedef unsigned int u32x4 __attribute__((ext_vector_type(4)));

static __device__ __forceinline__ unsigned short f2b(float x) {
    union { float f; unsigned int u; } c; c.f = x;
    unsigned int r = (c.u + 0x7FFFu + ((c.u >> 16) & 1u)) >> 16;
    return (unsigned short)r;
}

// ---------------- prep: normalize embeddings, echo layers, e0 (f32) + e0^T (bf16)
__global__ __launch_bounds__(256) void prep_norm(
        const float* __restrict__ emb, const float* __restrict__ freq,
        float* __restrict__ e0, unsigned short* __restrict__ eT0,
        int* __restrict__ echo) {
    __shared__ unsigned short tile[64][72];
    int t = threadIdx.x;
    int tok0 = blockIdx.x * 64;
    int lt = t >> 2;
    int tt = tok0 + lt;
    int dd = (t & 3) * 16;

    const float* src = emb + (size_t)tt * DD + dd;
    f32x4 v[4];
    float ss = 0.f;
    #pragma unroll
    for (int q = 0; q < 4; q++) {
        v[q] = *(const f32x4*)(src + q * 4);
        ss += v[q].x*v[q].x + v[q].y*v[q].y + v[q].z*v[q].z + v[q].w*v[q].w;
    }
    ss += __shfl_xor(ss, 1);
    ss += __shfl_xor(ss, 2);
    float scale = 1.f / fmaxf(sqrtf(ss), 1e-12f);
    float* dst = e0 + (size_t)tt * DD + dd;
    #pragma unroll
    for (int q = 0; q < 4; q++) {
        f32x4 o = v[q] * scale;
        *(f32x4*)(dst + q * 4) = o;
        tile[lt][dd + q*4 + 0] = f2b(o.x);
        tile[lt][dd + q*4 + 1] = f2b(o.y);
        tile[lt][dd + q*4 + 2] = f2b(o.z);
        tile[lt][dd + q*4 + 3] = f2b(o.w);
    }
    if ((t & 3) == 0) {
        int el = 1 + (int)floorf(freq[tt] * FREQ_SCALE);
        el = el < 1 ? 1 : (el > 5 ? 5 : el);
        echo[tt] = el;
    }
    __syncthreads();
    int b  = tok0 / NN;
    int tb = tok0 % NN;
    for (int idx = t; idx < 64 * 64; idx += 256) {
        int d = idx >> 6, j = idx & 63;
        eT0[((size_t)b * DD + d) * NN + tb + j] = tile[j][d];
    }
}

// ---------------- layer step
// 1024 threads = 16 waves: wi = w&3 (i-tile of 16 rows), kq = w>>2 (K quarter of 512).
// RD32: read fp32 rm, convert in-register, compute rowsum.  WR: also persist bf16 rm + rowsum.
template<bool RD32, bool WR>
__global__ __launch_bounds__(1024, 4) void layer_step(
        const void* __restrict__ rm_,
        const unsigned short* __restrict__ eT_src,  // [B][64][N] bf16
        const float* __restrict__ e_src,            // [B][N][64] f32
        const float* __restrict__ rowsum_g,
        const int* __restrict__ echo,
        float* __restrict__ e_dst,
        unsigned short* __restrict__ eT_dst,
        unsigned short* __restrict__ rmb_out,
        float* __restrict__ rowsum_out,
        int layer) {
    __shared__ float redAcc[3][4][64][16];   // 48KB: K-quarter partials
    __shared__ float redRs[3][4][64];        // 3KB: rowsum partials

    int t = threadIdx.x;
    int w = t >> 6, l = t & 63;
    int b = blockIdx.y;
    int i0 = blockIdx.x * 64;
    int wi = w & 3;
    int kq = w >> 2;
    int lane_lo = l & 15, lane_hi = l >> 4;
    int i = i0 + wi * 16 + lane_lo;
    size_t gi = (size_t)b * NN + i;

    f32x4 acc[4] = {};
    float rsum = 0.f;
    size_t rm_row = gi * NN;
    int kbase = kq * (NN / 4) + 8 * lane_hi;

    // epilogue scalars preloaded to hide latency
    int echo_pre = echo[gi];
    float rs_glob = RD32 ? 0.f : rowsum_g[gi];

    // base pointers: all inner-loop offsets become immediates
    const unsigned short* eT_b = eT_src + (size_t)b * DD * NN;
    const unsigned short* ea0 = eT_b + (size_t)(lane_lo)      * NN + kbase;
    const unsigned short* ea1 = eT_b + (size_t)(16 + lane_lo) * NN + kbase;
    const unsigned short* ea2 = eT_b + (size_t)(32 + lane_lo) * NN + kbase;
    const unsigned short* ea3 = eT_b + (size_t)(48 + lane_lo) * NN + kbase;

    if constexpr (RD32) {
        const float* rmp = (const float*)rm_ + rm_row + kbase;
        unsigned short* wst = WR ? (rmb_out + rm_row + kbase) : (unsigned short*)0;
        f32x4 pa[4], pb[4];
        #pragma unroll
        for (int j = 0; j < 4; j++) {
            pa[j] = *(const f32x4*)(rmp + 32 * j);
            pb[j] = *(const f32x4*)(rmp + 32 * j + 4);
        }
        #pragma unroll
        for (int j = 0; j < 16; j++) {
            f32x4 lo = pa[j & 3], hi = pb[j & 3];
            if (j < 12) {
                pa[j & 3] = *(const f32x4*)(rmp + 32 * (j + 4));
                pb[j & 3] = *(const f32x4*)(rmp + 32 * (j + 4) + 4);
            }
            u32x4 o;
            o.x = (unsigned)f2b(lo.x) | ((unsigned)f2b(lo.y) << 16);
            o.y = (unsigned)f2b(lo.z) | ((unsigned)f2b(lo.w) << 16);
            o.z = (unsigned)f2b(hi.x) | ((unsigned)f2b(hi.y) << 16);
            o.w = (unsigned)f2b(hi.z) | ((unsigned)f2b(hi.w) << 16);
            if constexpr (WR) *(u32x4*)(wst + 32 * j) = o;
            rsum += ((lo.x + lo.y) + (lo.z + lo.w)) + ((hi.x + hi.y) + (hi.z + hi.w));
            bf16x8 bfrag = __builtin_bit_cast(bf16x8, o);
            bf16x8 a0 = __builtin_bit_cast(bf16x8, *(const u32x4*)(ea0 + 32 * j));
            bf16x8 a1 = __builtin_bit_cast(bf16x8, *(const u32x4*)(ea1 + 32 * j));
            bf16x8 a2 = __builtin_bit_cast(bf16x8, *(const u32x4*)(ea2 + 32 * j));
            bf16x8 a3 = __builtin_bit_cast(bf16x8, *(const u32x4*)(ea3 + 32 * j));
            acc[0] = __builtin_amdgcn_mfma_f32_16x16x32_bf16(a0, bfrag, acc[0], 0, 0, 0);
            acc[1] = __builtin_amdgcn_mfma_f32_16x16x32_bf16(a1, bfrag, acc[1], 0, 0, 0);
            acc[2] = __builtin_amdgcn_mfma_f32_16x16x32_bf16(a2, bfrag, acc[2], 0, 0, 0);
            acc[3] = __builtin_amdgcn_mfma_f32_16x16x32_bf16(a3, bfrag, acc[3], 0, 0, 0);
        }
    } else {
        const unsigned short* rmp = (const unsigned short*)rm_ + rm_row + kbase;
        bf16x8 pf[4];
        #pragma unroll
        for (int j = 0; j < 4; j++)
            pf[j] = __builtin_bit_cast(bf16x8, *(const u32x4*)(rmp + 32 * j));
        #pragma unroll
        for (int j = 0; j < 16; j++) {
            bf16x8 bfrag = pf[j & 3];
            if (j < 12)
                pf[j & 3] = __builtin_bit_cast(bf16x8, *(const u32x4*)(rmp + 32 * (j + 4)));
            bf16x8 a0 = __builtin_bit_cast(bf16x8, *(const u32x4*)(ea0 + 32 * j));
            bf16x8 a1 = __builtin_bit_cast(bf16x8, *(const u32x4*)(ea1 + 32 * j));
            bf16x8 a2 = __builtin_bit_cast(bf16x8, *(const u32x4*)(ea2 + 32 * j));
            bf16x8 a3 = __builtin_bit_cast(bf16x8, *(const u32x4*)(ea3 + 32 * j));
            acc[0] = __builtin_amdgcn_mfma_f32_16x16x32_bf16(a0, bfrag, acc[0], 0, 0, 0);
            acc[1] = __builtin_amdgcn_mfma_f32_16x16x32_bf16(a1, bfrag, acc[1], 0, 0, 0);
            acc[2] = __builtin_amdgcn_mfma_f32_16x16x32_bf16(a2, bfrag, acc[2], 0, 0, 0);
            acc[3] = __builtin_amdgcn_mfma_f32_16x16x32_bf16(a3, bfrag, acc[3], 0, 0, 0);
        }
    }

    if constexpr (RD32) {
        rsum += __shfl_xor(rsum, 16);
        rsum += __shfl_xor(rsum, 32);
    }

    if (kq > 0) {
        float* dp = &redAcc[kq - 1][wi][l][0];
        #pragma unroll
        for (int f = 0; f < 4; f++) *(f32x4*)(dp + 4 * f) = acc[f];
        if constexpr (RD32) redRs[kq - 1][wi][l] = rsum;
    }
    __syncthreads();
    if (kq == 0) {
        const float* sp = &redAcc[0][wi][l][0];
        #pragma unroll
        for (int f = 0; f < 4; f++) {
            acc[f] += *(const f32x4*)(&redAcc[0][wi][l][4 * f]);
            acc[f] += *(const f32x4*)(&redAcc[1][wi][l][4 * f]);
            acc[f] += *(const f32x4*)(&redAcc[2][wi][l][4 * f]);
        }
        (void)sp;
        float rs;
        if constexpr (RD32) {
            rsum += redRs[0][wi][l] + redRs[1][wi][l] + redRs[2][wi][l];
            rs = rsum;
            if constexpr (WR) { if (l < 16) rowsum_out[(size_t)b * NN + i0 + wi * 16 + l] = 0.f; }
        } else {
            rs = rs_glob;
        }
        // stash full rowsum (any lane_hi has same value after shfl; lane_lo indexes row)
        if constexpr (RD32 && WR) {
            if (lane_hi == 0) rowsum_out[gi] = rs;
        }

        float active = (layer < echo_pre) ? 1.f : 0.f;
        float coef = DELTA * active;
        size_t ebase = gi * DD;
        f32x4 upd[4];
        float ss = 0.f;
        #pragma unroll
        for (int f = 0; f < 4; f++) {
            f32x4 e = *(const f32x4*)(e_src + ebase + 16 * f + 4 * lane_hi);
            f32x4 u = e + coef * (e * rs - acc[f]);
            upd[f] = u;
            ss += u.x*u.x + u.y*u.y + u.z*u.z + u.w*u.w;
        }
        ss += __shfl_xor(ss, 16);
        ss += __shfl_xor(ss, 32);
        float scale = 1.f / fmaxf(sqrtf(ss), 1e-12f);
        unsigned short* ep = eT_dst + (size_t)b * DD * NN;
        #pragma unroll
        for (int f = 0; f < 4; f++) {
            f32x4 o = upd[f] * scale;
            *(f32x4*)(e_dst + ebase + 16 * f + 4 * lane_hi) = o;
            int dbase = 16 * f + 4 * lane_hi;
            ep[(size_t)(dbase + 0) * NN + i] = f2b(o.x);
            ep[(size_t)(dbase + 1) * NN + i] = f2b(o.y);
            ep[(size_t)(dbase + 2) * NN + i] = f2b(o.z);
            ep[(size_t)(dbase + 3) * NN + i] = f2b(o.w);
        }
    }
}

extern "C" void kernel_launch(void* const* d_in, const int* in_sizes, int n_in,
                              void* d_out, int out_size, void* d_ws, size_t ws_size,
                              hipStream_t stream) {
    const float* emb  = (const float*)d_in[0];
    const float* freq = (const float*)d_in[1];
    const float* rm   = (const float*)d_in[2];
    float* out = (float*)d_out;
    char* ws = (char*)d_ws;

    const size_t eBytes   = (size_t)BB * NN * DD * 4;   // 4 MB
    const size_t eTBytes  = (size_t)BB * DD * NN * 2;   // 2 MB
    const size_t bnBytes  = (size_t)BB * NN * 4;        // 64 KB
    const size_t rmbBytes = (size_t)BB * NN * NN * 2;   // 67 MB
    float* e_f32[2] = { (float*)ws, (float*)(ws + eBytes) };
    unsigned short* eT[2] = { (unsigned short*)(ws + 2*eBytes),
                              (unsigned short*)(ws + 2*eBytes + eTBytes) };
    float* rowsum = (float*)(ws + 2*eBytes + 2*eTBytes);
    int* echo = (int*)(ws + 2*eBytes + 2*eTBytes + bnBytes);
    unsigned short* rmb = (unsigned short*)(ws + 2*eBytes + 2*eTBytes + 2*bnBytes);
    size_t need_cached = 2*eBytes + 2*eTBytes + 2*bnBytes + rmbBytes;
    int cached = (ws_size >= need_cached) ? 1 : 0;

    prep_norm<<<dim3(BB*NN/64), dim3(256), 0, stream>>>(emb, freq, e_f32[0], eT[0], echo);

    dim3 lgrid(NN/64, BB), lblk(1024);
    if (cached) {
        // layer 0: read fp32 rm, emit bf16 rm cache + rowsum
        layer_step<true, true><<<lgrid, lblk, 0, stream>>>(
            (const void*)rm, eT[0], e_f32[0], nullptr, echo,
            e_f32[1], eT[1], rmb, rowsum, 0);
        for (int l = 1; l < 5; l++) {
            float* dst = (l == 4) ? out : e_f32[(l + 1) & 1];
            layer_step<false, false><<<lgrid, lblk, 0, stream>>>(
                (const void*)rmb, eT[l & 1], e_f32[l & 1], rowsum, echo,
                dst, eT[(l + 1) & 1], nullptr, nullptr, l);
        }
    } else {
        for (int l = 0; l < 5; l++) {
            float* dst = (l == 4) ? out : e_f32[(l + 1) & 1];
            layer_step<true, false><<<lgrid, lblk, 0, stream>>>(
                (const void*)rm, eT[l & 1], e_f32[l & 1], nullptr, echo,
                dst, eT[(l + 1) & 1], nullptr, nullptr, l);
        }
    }
}